// Round 1
// baseline (43252.448 us; speedup 1.0000x reference)
//
#include <hip/hip_runtime.h>

// ---------------------------------------------------------------------------
// NS_Flashed_TotalSimRetina — GLM retina simulation, round 6.
// Structural change: batches are independent (coupling is intra-batch only),
// so the device-wide software barrier (75 wgs, agent-scope ring + atomic
// counter + MALL polling; ~30 us/step of coherence latency) is replaced by
// one workgroup per batch:
//   32 wgs x 600 threads (thread = cell). Spike exchange through a 2.4 KB
//   LDS double buffer + one __syncthreads per step. No atomics, no ring.
// Weight table transposed to wPT[i4][c] so per-lane streams are coalesced
// (lane c reads consecutive uint4s); 2.64 MB table stays L2-resident.
// ---------------------------------------------------------------------------

#define NC     600
#define NPIX   4096
#define NBF    100
#define MC     20
#define NB     500
#define NBI    100
#define NBATCH 32
#define NSTEP  400

typedef unsigned int u32;
typedef _Float16 f16x2 __attribute__((ext_vector_type(2)));

__device__ __forceinline__ float dot2(u32 a, u32 b, float acc) {
  return __builtin_amdgcn_fdot2(__builtin_bit_cast(f16x2, a),
                                __builtin_bit_cast(f16x2, b), acc, false);
}
__device__ __forceinline__ u32 pkrtz(float a, float b) {
  return __builtin_bit_cast(u32, __builtin_amdgcn_cvt_pkrtz(a, b));
}

// --- stim_applied[b][c] = sum_p stim[b][p] * spat[c][p] ---------------------
__global__ void applied_kernel(const float* __restrict__ stim,
                               const float* __restrict__ spat,
                               float* __restrict__ applied) {
  const int c = blockIdx.x, b = blockIdx.y;
  __shared__ float red[256];
  float a = 0.f;
  for (int p = threadIdx.x; p < NPIX; p += 256)
    a += stim[b * NPIX + p] * spat[c * NPIX + p];
  red[threadIdx.x] = a;
  __syncthreads();
  for (int s = 128; s > 0; s >>= 1) {
    if (threadIdx.x < s) red[threadIdx.x] += red[threadIdx.x + s];
    __syncthreads();
  }
  if (threadIdx.x == 0) applied[b * NC + c] = red[0];
}

// --- convT[t][c] = sum_f stc[t+f] * tcf[c][f] ------------------------------
__global__ void conv_kernel(const float* __restrict__ stc,
                            const float* __restrict__ tcf,
                            float* __restrict__ convT) {
  int idx = blockIdx.x * 256 + threadIdx.x;
  if (idx >= NSTEP * NC) return;
  int t = idx / NC, c = idx - t * NC;
  float a = 0.f;
  for (int f = 0; f < NBF; ++f)
    a += stc[t + f] * tcf[c * NBF + f];
  convT[idx] = a;
}

// --- packed, time-reversed, edge-paired, CELL-TRANSPOSED filter table ------
// Logical per-cell stream: pair p<10 -> (cf[c][2p][99-i], cf[c][2p+1][99-i]);
// p==10 -> (ff[c][99-i], 0).   Stored so that the uint4 holding taps
// [4k .. 4k+3] of pair p for cell c sits at uint4 index (p*25 + k)*NC + c:
// lane c reads consecutive uint4s -> fully coalesced 16 B/lane.
__global__ void pack_kernel(const float* __restrict__ cf,
                            const float* __restrict__ ff,
                            u32* __restrict__ wPT) {
  int idx = blockIdx.x * 256 + threadIdx.x;
  if (idx >= NC * 1100) return;
  int c = idx / 1100;
  int r = idx - c * 1100;
  int p = r / 100;
  int i = r - p * 100;
  int f = 99 - i;
  float lo, hi;
  if (p < 10) {
    lo = cf[(c * MC + 2 * p) * NBF + f];
    hi = cf[(c * MC + 2 * p + 1) * NBF + f];
  } else {
    lo = ff[c * NBF + f];
    hi = 0.f;
  }
  wPT[((p * 25 + (i >> 2)) * NC + c) * 4 + (i & 3)] = pkrtz(lo, hi);
}

// --- packed source pairs, transposed: selpT[p][c] = src0 | (src1 << 16) ----
__global__ void selp_kernel(const int* __restrict__ sel, u32* __restrict__ selpT) {
  int idx = blockIdx.x * 256 + threadIdx.x;
  if (idx >= NC * 10) return;
  int c = idx / 10, p = idx - c * 10;
  u32 s0 = (u32)sel[c * MC + 2 * p];
  u32 s1 = (u32)sel[c * MC + 2 * p + 1];
  selpT[p * NC + c] = s0 | (s1 << 16);
}

// --- initT2[b][tau][c] = init[b][c][tau]  (coalesced per-step reads) -------
__global__ void initT2_kernel(const float* __restrict__ init,
                              float* __restrict__ initT2) {
  int idx = blockIdx.x * 256 + threadIdx.x;
  if (idx >= NBATCH * NBI * NC) return;
  int c = idx % NC;
  int r = idx / NC;
  int tau = r % NBI;
  int b = r / NBI;
  initT2[idx] = init[(b * NC + c) * NBI + tau];
}

// --- copy initial spikes into output (first 100 bins of each row) ----------
__global__ void copy_init_kernel(const float4* __restrict__ init,
                                 float4* __restrict__ out) {
  int idx = blockIdx.x * 256 + threadIdx.x;
  if (idx >= NBATCH * NC * (NBI / 4)) return;
  int k4 = idx % (NBI / 4);
  int bc = idx / (NBI / 4);
  out[bc * (NB / 4) + k4] = init[idx];
}

// --- the recurrence: one workgroup per batch, LDS spike exchange -----------
__global__ __launch_bounds__(NC) void sim_kernel(
    const float* __restrict__ bias, const float* __restrict__ applied,
    const float* __restrict__ convT, const uint4* __restrict__ wp,
    const u32* __restrict__ selpT, const float* __restrict__ initT2,
    float* __restrict__ out) {
  const int c = threadIdx.x;     // cell, 0..599
  const int b = blockIdx.x;      // batch, 0..31

  __shared__ float spk[2][NC];   // double-buffered current-step spikes

  float acc[NBF];
#pragma unroll
  for (int i = 0; i < NBF; ++i) acc[i] = 0.f;

  u32 selpv[10];
#pragma unroll
  for (int p = 0; p < 10; ++p) selpv[p] = selpT[p * NC + c];  // coalesced

  const float biasv = bias[c];
  const float appv  = applied[b * NC + c];
  const float* ib2  = initT2 + (size_t)b * NBI * NC;
  float* outS = out + (size_t)(b * NC + c) * NB + NBI;
  float* outG = out + (size_t)NBATCH * NC * NB + (size_t)(b * NC + c) * NSTEP;

#pragma unroll 1
  for (int tau = 0; tau < NB; ++tau) {
    const int t  = tau - NBI;
    const int pb = tau & 1;
    float sv;
    if (t >= 0) {
      float g = biasv + appv * convT[t * NC + c] + acc[0];
      sv = 1.f / (1.f + __expf(-g));
      outS[t] = sv;
      outG[t] = g;
    } else {
      sv = ib2[tau * NC + c];
    }
    spk[pb][c] = sv;

    // rotate: acc[i] <- contributions to step (tau+1)+i
#pragma unroll
    for (int i = 0; i < NBF - 1; ++i) acc[i] = acc[i + 1];
    acc[NBF - 1] = 0.f;

    // feedback scatter (own spike, local data) — before the barrier
    {
      const u32 sp10 = pkrtz(sv, 0.f);
#pragma unroll
      for (int ib = 0; ib < 25; ++ib) {
        const uint4 w = wp[(250 + ib) * NC + c];
        acc[ib * 4 + 0] = dot2(w.x, sp10, acc[ib * 4 + 0]);
        acc[ib * 4 + 1] = dot2(w.y, sp10, acc[ib * 4 + 1]);
        acc[ib * 4 + 2] = dot2(w.z, sp10, acc[ib * 4 + 2]);
        acc[ib * 4 + 3] = dot2(w.w, sp10, acc[ib * 4 + 3]);
      }
    }

    __syncthreads();   // all 600 spikes of this batch now visible in LDS

    // coupling scatter: gather 20 spikes from LDS, 1000 dot2
#pragma unroll
    for (int p = 0; p < 10; ++p) {
      const u32 s01 = selpv[p];
      const u32 sp2 = pkrtz(spk[pb][s01 & 0xffffu], spk[pb][s01 >> 16]);
#pragma unroll
      for (int ib = 0; ib < 25; ++ib) {
        const uint4 w = wp[(p * 25 + ib) * NC + c];
        acc[ib * 4 + 0] = dot2(w.x, sp2, acc[ib * 4 + 0]);
        acc[ib * 4 + 1] = dot2(w.y, sp2, acc[ib * 4 + 1]);
        acc[ib * 4 + 2] = dot2(w.z, sp2, acc[ib * 4 + 2]);
        acc[ib * 4 + 3] = dot2(w.w, sp2, acc[ib * 4 + 3]);
      }
    }
    // no second barrier needed: next write touches spk[pb^1]; the next
    // iteration's __syncthreads orders it before any reuse of spk[pb].
  }
}

extern "C" void kernel_launch(void* const* d_in, const int* in_sizes, int n_in,
                              void* d_out, int out_size, void* d_ws, size_t ws_size,
                              hipStream_t stream) {
  const float* stim = (const float*)d_in[0];   // 32x64x64
  const float* init = (const float*)d_in[1];   // 32x600x100
  const float* spat = (const float*)d_in[2];   // 600x4096
  const float* tcf  = (const float*)d_in[3];   // 600x100
  const float* ff   = (const float*)d_in[4];   // 600x100
  const float* cf   = (const float*)d_in[5];   // 600x20x100
  const float* bias = (const float*)d_in[6];   // 600x1
  const int*   sel  = (const int*)d_in[7];     // 600x20 int32
  const float* stc  = (const float*)d_in[8];   // 500
  float* out = (float*)d_out;                  // spikes 32x600x500, gensig 32x600x400

  char* ws = (char*)d_ws;
  float* applied = (float*)ws;                       //     76,800 B
  float* convT   = (float*)(ws + 76800);             //    960,000 B
  u32*   wPT     = (u32*)(ws + 1036800);             //  2,640,000 B
  u32*   selpT   = (u32*)(ws + 3676800);             //     24,000 B
  float* initT2  = (float*)(ws + 3700800);           //  7,680,000 B (end ~11.4 MB)
  (void)ws_size; (void)in_sizes; (void)n_in; (void)out_size;

  hipLaunchKernelGGL(applied_kernel, dim3(NC, NBATCH), dim3(256), 0, stream,
                     stim, spat, applied);
  hipLaunchKernelGGL(conv_kernel, dim3((NSTEP * NC + 255) / 256), dim3(256), 0,
                     stream, stc, tcf, convT);
  hipLaunchKernelGGL(pack_kernel, dim3((NC * 1100 + 255) / 256), dim3(256), 0,
                     stream, cf, ff, wPT);
  hipLaunchKernelGGL(selp_kernel, dim3((NC * 10 + 255) / 256), dim3(256), 0,
                     stream, sel, selpT);
  hipLaunchKernelGGL(initT2_kernel, dim3((NBATCH * NBI * NC + 255) / 256),
                     dim3(256), 0, stream, init, initT2);
  hipLaunchKernelGGL(copy_init_kernel,
                     dim3((NBATCH * NC * (NBI / 4) + 255) / 256), dim3(256), 0,
                     stream, (const float4*)init, (float4*)out);
  hipLaunchKernelGGL(sim_kernel, dim3(NBATCH), dim3(NC), 0, stream,
                     bias, applied, convT, (const uint4*)wPT, selpT, initT2, out);
}

// Round 2
// 30365.601 us; speedup vs baseline: 1.4244x; 1.4244x over previous
//
#include <hip/hip_runtime.h>

// ---------------------------------------------------------------------------
// NS_Flashed_TotalSimRetina — GLM retina simulation, round 7.
// Round-6 structure (one workgroup per batch, LDS spike exchange) was right,
// but VGPR_Count=84 proved acc[100] spilled to scratch: scratch RMW
// serialized the inner loop (VALUBusy 0.77%) and the ~1MB/XCD scratch set
// evicted the 2.64MB weight table from L2 (FETCH 20.3 GB from HBM).
// Fixes:
//   - __launch_bounds__(600, 1): allocator targets 1 wave/EU; workgroup-fit
//     caps VGPRs at ~170, enough for acc[100]+temps (round-5 codegen: 136).
//   - pair loop back to "#pragma unroll 1" (proven round-5 shape, bounded
//     load-pipeline register pressure); LDS spike gathers hoisted into sp[10]
//     ahead of the weight loop.
// Expected: weights L2-resident, VALU/L2-BW co-limited, ~2.5 us/step.
// ---------------------------------------------------------------------------

#define NC     600
#define NPIX   4096
#define NBF    100
#define MC     20
#define NB     500
#define NBI    100
#define NBATCH 32
#define NSTEP  400

typedef unsigned int u32;
typedef _Float16 f16x2 __attribute__((ext_vector_type(2)));

__device__ __forceinline__ float dot2(u32 a, u32 b, float acc) {
  return __builtin_amdgcn_fdot2(__builtin_bit_cast(f16x2, a),
                                __builtin_bit_cast(f16x2, b), acc, false);
}
__device__ __forceinline__ u32 pkrtz(float a, float b) {
  return __builtin_bit_cast(u32, __builtin_amdgcn_cvt_pkrtz(a, b));
}

// --- stim_applied[b][c] = sum_p stim[b][p] * spat[c][p] ---------------------
__global__ void applied_kernel(const float* __restrict__ stim,
                               const float* __restrict__ spat,
                               float* __restrict__ applied) {
  const int c = blockIdx.x, b = blockIdx.y;
  __shared__ float red[256];
  float a = 0.f;
  for (int p = threadIdx.x; p < NPIX; p += 256)
    a += stim[b * NPIX + p] * spat[c * NPIX + p];
  red[threadIdx.x] = a;
  __syncthreads();
  for (int s = 128; s > 0; s >>= 1) {
    if (threadIdx.x < s) red[threadIdx.x] += red[threadIdx.x + s];
    __syncthreads();
  }
  if (threadIdx.x == 0) applied[b * NC + c] = red[0];
}

// --- convT[t][c] = sum_f stc[t+f] * tcf[c][f] ------------------------------
__global__ void conv_kernel(const float* __restrict__ stc,
                            const float* __restrict__ tcf,
                            float* __restrict__ convT) {
  int idx = blockIdx.x * 256 + threadIdx.x;
  if (idx >= NSTEP * NC) return;
  int t = idx / NC, c = idx - t * NC;
  float a = 0.f;
  for (int f = 0; f < NBF; ++f)
    a += stc[t + f] * tcf[c * NBF + f];
  convT[idx] = a;
}

// --- packed, time-reversed, edge-paired, CELL-TRANSPOSED filter table ------
// Logical per-cell stream: pair p<10 -> (cf[c][2p][99-i], cf[c][2p+1][99-i]);
// p==10 -> (ff[c][99-i], 0).   Stored so that the uint4 holding taps
// [4k .. 4k+3] of pair p for cell c sits at uint4 index (p*25 + k)*NC + c:
// lane c reads consecutive uint4s -> fully coalesced 16 B/lane.
__global__ void pack_kernel(const float* __restrict__ cf,
                            const float* __restrict__ ff,
                            u32* __restrict__ wPT) {
  int idx = blockIdx.x * 256 + threadIdx.x;
  if (idx >= NC * 1100) return;
  int c = idx / 1100;
  int r = idx - c * 1100;
  int p = r / 100;
  int i = r - p * 100;
  int f = 99 - i;
  float lo, hi;
  if (p < 10) {
    lo = cf[(c * MC + 2 * p) * NBF + f];
    hi = cf[(c * MC + 2 * p + 1) * NBF + f];
  } else {
    lo = ff[c * NBF + f];
    hi = 0.f;
  }
  wPT[((p * 25 + (i >> 2)) * NC + c) * 4 + (i & 3)] = pkrtz(lo, hi);
}

// --- packed source pairs, transposed: selpT[p][c] = src0 | (src1 << 16) ----
__global__ void selp_kernel(const int* __restrict__ sel, u32* __restrict__ selpT) {
  int idx = blockIdx.x * 256 + threadIdx.x;
  if (idx >= NC * 10) return;
  int c = idx / 10, p = idx - c * 10;
  u32 s0 = (u32)sel[c * MC + 2 * p];
  u32 s1 = (u32)sel[c * MC + 2 * p + 1];
  selpT[p * NC + c] = s0 | (s1 << 16);
}

// --- initT2[b][tau][c] = init[b][c][tau]  (coalesced per-step reads) -------
__global__ void initT2_kernel(const float* __restrict__ init,
                              float* __restrict__ initT2) {
  int idx = blockIdx.x * 256 + threadIdx.x;
  if (idx >= NBATCH * NBI * NC) return;
  int c = idx % NC;
  int r = idx / NC;
  int tau = r % NBI;
  int b = r / NBI;
  initT2[idx] = init[(b * NC + c) * NBI + tau];
}

// --- copy initial spikes into output (first 100 bins of each row) ----------
__global__ void copy_init_kernel(const float4* __restrict__ init,
                                 float4* __restrict__ out) {
  int idx = blockIdx.x * 256 + threadIdx.x;
  if (idx >= NBATCH * NC * (NBI / 4)) return;
  int k4 = idx % (NBI / 4);
  int bc = idx / (NBI / 4);
  out[bc * (NB / 4) + k4] = init[idx];
}

// --- the recurrence: one workgroup per batch, LDS spike exchange -----------
__global__ __launch_bounds__(NC, 1) void sim_kernel(
    const float* __restrict__ bias, const float* __restrict__ applied,
    const float* __restrict__ convT, const uint4* __restrict__ wp,
    const u32* __restrict__ selpT, const float* __restrict__ initT2,
    float* __restrict__ out) {
  const int c = threadIdx.x;     // cell, 0..599
  const int b = blockIdx.x;      // batch, 0..31

  __shared__ float spk[2][NC];   // double-buffered current-step spikes

  float acc[NBF];
#pragma unroll
  for (int i = 0; i < NBF; ++i) acc[i] = 0.f;

  u32 selpv[10];
#pragma unroll
  for (int p = 0; p < 10; ++p) selpv[p] = selpT[p * NC + c];  // coalesced

  const float biasv = bias[c];
  const float appv  = applied[b * NC + c];
  const float* ib2  = initT2 + (size_t)b * NBI * NC;
  float* outS = out + (size_t)(b * NC + c) * NB + NBI;
  float* outG = out + (size_t)NBATCH * NC * NB + (size_t)(b * NC + c) * NSTEP;

#pragma unroll 1
  for (int tau = 0; tau < NB; ++tau) {
    const int t  = tau - NBI;
    const int pb = tau & 1;
    float sv;
    if (t >= 0) {
      float g = biasv + appv * convT[t * NC + c] + acc[0];
      sv = 1.f / (1.f + __expf(-g));
      outS[t] = sv;
      outG[t] = g;
    } else {
      sv = ib2[tau * NC + c];
    }
    spk[pb][c] = sv;

    // rotate: acc[i] <- contributions to step (tau+1)+i
#pragma unroll
    for (int i = 0; i < NBF - 1; ++i) acc[i] = acc[i + 1];
    acc[NBF - 1] = 0.f;

    // feedback scatter (own spike, local data) — before the barrier
    {
      const u32 sp10 = pkrtz(sv, 0.f);
#pragma unroll
      for (int ib = 0; ib < 25; ++ib) {
        const uint4 w = wp[(250 + ib) * NC + c];
        acc[ib * 4 + 0] = dot2(w.x, sp10, acc[ib * 4 + 0]);
        acc[ib * 4 + 1] = dot2(w.y, sp10, acc[ib * 4 + 1]);
        acc[ib * 4 + 2] = dot2(w.z, sp10, acc[ib * 4 + 2]);
        acc[ib * 4 + 3] = dot2(w.w, sp10, acc[ib * 4 + 3]);
      }
    }

    __syncthreads();   // all 600 spikes of this batch now visible in LDS

    // gather all 20 coupled spikes first (LDS latency off the p-loop path)
    u32 sp[10];
#pragma unroll
    for (int p = 0; p < 10; ++p) {
      const u32 s01 = selpv[p];
      sp[p] = pkrtz(spk[pb][s01 & 0xffffu], spk[pb][s01 >> 16]);
    }

    // coupling scatter: acc[i] += w[p][i] . sp[p]   (1000 dot2)
#pragma unroll 1
    for (int p = 0; p < 10; ++p) {
      const u32 sp2 = sp[p];
#pragma unroll
      for (int ib = 0; ib < 25; ++ib) {
        const uint4 w = wp[(p * 25 + ib) * NC + c];
        acc[ib * 4 + 0] = dot2(w.x, sp2, acc[ib * 4 + 0]);
        acc[ib * 4 + 1] = dot2(w.y, sp2, acc[ib * 4 + 1]);
        acc[ib * 4 + 2] = dot2(w.z, sp2, acc[ib * 4 + 2]);
        acc[ib * 4 + 3] = dot2(w.w, sp2, acc[ib * 4 + 3]);
      }
    }
    // no second barrier needed: next write touches spk[pb^1]; the next
    // iteration's __syncthreads orders it before any reuse of spk[pb].
  }
}

extern "C" void kernel_launch(void* const* d_in, const int* in_sizes, int n_in,
                              void* d_out, int out_size, void* d_ws, size_t ws_size,
                              hipStream_t stream) {
  const float* stim = (const float*)d_in[0];   // 32x64x64
  const float* init = (const float*)d_in[1];   // 32x600x100
  const float* spat = (const float*)d_in[2];   // 600x4096
  const float* tcf  = (const float*)d_in[3];   // 600x100
  const float* ff   = (const float*)d_in[4];   // 600x100
  const float* cf   = (const float*)d_in[5];   // 600x20x100
  const float* bias = (const float*)d_in[6];   // 600x1
  const int*   sel  = (const int*)d_in[7];     // 600x20 int32
  const float* stc  = (const float*)d_in[8];   // 500
  float* out = (float*)d_out;                  // spikes 32x600x500, gensig 32x600x400

  char* ws = (char*)d_ws;
  float* applied = (float*)ws;                       //     76,800 B
  float* convT   = (float*)(ws + 76800);             //    960,000 B
  u32*   wPT     = (u32*)(ws + 1036800);             //  2,640,000 B
  u32*   selpT   = (u32*)(ws + 3676800);             //     24,000 B
  float* initT2  = (float*)(ws + 3700800);           //  7,680,000 B (end ~11.4 MB)
  (void)ws_size; (void)in_sizes; (void)n_in; (void)out_size;

  hipLaunchKernelGGL(applied_kernel, dim3(NC, NBATCH), dim3(256), 0, stream,
                     stim, spat, applied);
  hipLaunchKernelGGL(conv_kernel, dim3((NSTEP * NC + 255) / 256), dim3(256), 0,
                     stream, stc, tcf, convT);
  hipLaunchKernelGGL(pack_kernel, dim3((NC * 1100 + 255) / 256), dim3(256), 0,
                     stream, cf, ff, wPT);
  hipLaunchKernelGGL(selp_kernel, dim3((NC * 10 + 255) / 256), dim3(256), 0,
                     stream, sel, selpT);
  hipLaunchKernelGGL(initT2_kernel, dim3((NBATCH * NBI * NC + 255) / 256),
                     dim3(256), 0, stream, init, initT2);
  hipLaunchKernelGGL(copy_init_kernel,
                     dim3((NBATCH * NC * (NBI / 4) + 255) / 256), dim3(256), 0,
                     stream, (const float4*)init, (float4*)out);
  hipLaunchKernelGGL(sim_kernel, dim3(NBATCH), dim3(NC), 0, stream,
                     bias, applied, convT, (const uint4*)wPT, selpT, initT2, out);
}

// Round 3
// 28563.956 us; speedup vs baseline: 1.5142x; 1.0631x over previous
//
#include <hip/hip_runtime.h>

// ---------------------------------------------------------------------------
// NS_Flashed_TotalSimRetina — GLM retina simulation, round 8.
// Rounds 6/7 proved the one-wg-per-batch LDS-exchange structure but hit a
// register-allocator failure: VGPR_Count=84 (= 512/6: the allocator spilled
// acc[100] to scratch chasing 6 waves/EU, an occupancy that can't exist —
// only one 10-wave wg fits per CU, 3/3/2/2 across SIMDs). Scratch RMW
// serialized everything (VALUBusy 12% on active CUs, WRITE_SIZE ~1 GB of
// scratch leak).
// Fix: pin the allocator with amdgpu attrs instead of __launch_bounds__:
//   amdgpu_flat_work_group_size(600,600) + amdgpu_waves_per_eu(3,3)
//   -> budget 512/3 = 170 VGPRs (the launchable max for a 10-wave wg),
//   scheduler occupancy target pinned at 3 so it stops spilling.
// Plus ~10 VGPRs of margin: sp[] hoist dropped (per-pair LDS gather inside
// the p-loop; 25 weight loads + 100 dot2 per iter hide the LDS latency).
// Expected: acc[100] in registers, VALU/L2-BW co-limited, ~3 us/step.
// ---------------------------------------------------------------------------

#define NC     600
#define NPIX   4096
#define NBF    100
#define MC     20
#define NB     500
#define NBI    100
#define NBATCH 32
#define NSTEP  400

typedef unsigned int u32;
typedef _Float16 f16x2 __attribute__((ext_vector_type(2)));

__device__ __forceinline__ float dot2(u32 a, u32 b, float acc) {
  return __builtin_amdgcn_fdot2(__builtin_bit_cast(f16x2, a),
                                __builtin_bit_cast(f16x2, b), acc, false);
}
__device__ __forceinline__ u32 pkrtz(float a, float b) {
  return __builtin_bit_cast(u32, __builtin_amdgcn_cvt_pkrtz(a, b));
}

// --- stim_applied[b][c] = sum_p stim[b][p] * spat[c][p] ---------------------
__global__ void applied_kernel(const float* __restrict__ stim,
                               const float* __restrict__ spat,
                               float* __restrict__ applied) {
  const int c = blockIdx.x, b = blockIdx.y;
  __shared__ float red[256];
  float a = 0.f;
  for (int p = threadIdx.x; p < NPIX; p += 256)
    a += stim[b * NPIX + p] * spat[c * NPIX + p];
  red[threadIdx.x] = a;
  __syncthreads();
  for (int s = 128; s > 0; s >>= 1) {
    if (threadIdx.x < s) red[threadIdx.x] += red[threadIdx.x + s];
    __syncthreads();
  }
  if (threadIdx.x == 0) applied[b * NC + c] = red[0];
}

// --- convT[t][c] = sum_f stc[t+f] * tcf[c][f] ------------------------------
__global__ void conv_kernel(const float* __restrict__ stc,
                            const float* __restrict__ tcf,
                            float* __restrict__ convT) {
  int idx = blockIdx.x * 256 + threadIdx.x;
  if (idx >= NSTEP * NC) return;
  int t = idx / NC, c = idx - t * NC;
  float a = 0.f;
  for (int f = 0; f < NBF; ++f)
    a += stc[t + f] * tcf[c * NBF + f];
  convT[idx] = a;
}

// --- packed, time-reversed, edge-paired, CELL-TRANSPOSED filter table ------
// Logical per-cell stream: pair p<10 -> (cf[c][2p][99-i], cf[c][2p+1][99-i]);
// p==10 -> (ff[c][99-i], 0).   Stored so that the uint4 holding taps
// [4k .. 4k+3] of pair p for cell c sits at uint4 index (p*25 + k)*NC + c:
// lane c reads consecutive uint4s -> fully coalesced 16 B/lane.
__global__ void pack_kernel(const float* __restrict__ cf,
                            const float* __restrict__ ff,
                            u32* __restrict__ wPT) {
  int idx = blockIdx.x * 256 + threadIdx.x;
  if (idx >= NC * 1100) return;
  int c = idx / 1100;
  int r = idx - c * 1100;
  int p = r / 100;
  int i = r - p * 100;
  int f = 99 - i;
  float lo, hi;
  if (p < 10) {
    lo = cf[(c * MC + 2 * p) * NBF + f];
    hi = cf[(c * MC + 2 * p + 1) * NBF + f];
  } else {
    lo = ff[c * NBF + f];
    hi = 0.f;
  }
  wPT[((p * 25 + (i >> 2)) * NC + c) * 4 + (i & 3)] = pkrtz(lo, hi);
}

// --- packed source pairs, transposed: selpT[p][c] = src0 | (src1 << 16) ----
__global__ void selp_kernel(const int* __restrict__ sel, u32* __restrict__ selpT) {
  int idx = blockIdx.x * 256 + threadIdx.x;
  if (idx >= NC * 10) return;
  int c = idx / 10, p = idx - c * 10;
  u32 s0 = (u32)sel[c * MC + 2 * p];
  u32 s1 = (u32)sel[c * MC + 2 * p + 1];
  selpT[p * NC + c] = s0 | (s1 << 16);
}

// --- initT2[b][tau][c] = init[b][c][tau]  (coalesced per-step reads) -------
__global__ void initT2_kernel(const float* __restrict__ init,
                              float* __restrict__ initT2) {
  int idx = blockIdx.x * 256 + threadIdx.x;
  if (idx >= NBATCH * NBI * NC) return;
  int c = idx % NC;
  int r = idx / NC;
  int tau = r % NBI;
  int b = r / NBI;
  initT2[idx] = init[(b * NC + c) * NBI + tau];
}

// --- copy initial spikes into output (first 100 bins of each row) ----------
__global__ void copy_init_kernel(const float4* __restrict__ init,
                                 float4* __restrict__ out) {
  int idx = blockIdx.x * 256 + threadIdx.x;
  if (idx >= NBATCH * NC * (NBI / 4)) return;
  int k4 = idx % (NBI / 4);
  int bc = idx / (NBI / 4);
  out[bc * (NB / 4) + k4] = init[idx];
}

// --- the recurrence: one workgroup per batch, LDS spike exchange -----------
__global__ __attribute__((amdgpu_flat_work_group_size(600, 600)))
__attribute__((amdgpu_waves_per_eu(3, 3)))
void sim_kernel(
    const float* __restrict__ bias, const float* __restrict__ applied,
    const float* __restrict__ convT, const uint4* __restrict__ wp,
    const u32* __restrict__ selpT, const float* __restrict__ initT2,
    float* __restrict__ out) {
  const int c = threadIdx.x;     // cell, 0..599
  const int b = blockIdx.x;      // batch, 0..31

  __shared__ float spk[2][NC];   // double-buffered current-step spikes

  float acc[NBF];
#pragma unroll
  for (int i = 0; i < NBF; ++i) acc[i] = 0.f;

  u32 selpv[10];
#pragma unroll
  for (int p = 0; p < 10; ++p) selpv[p] = selpT[p * NC + c];  // coalesced

  const float biasv = bias[c];
  const float appv  = applied[b * NC + c];
  const float* ib2  = initT2 + (size_t)b * NBI * NC;
  float* outS = out + (size_t)(b * NC + c) * NB + NBI;
  float* outG = out + (size_t)NBATCH * NC * NB + (size_t)(b * NC + c) * NSTEP;

#pragma unroll 1
  for (int tau = 0; tau < NB; ++tau) {
    const int t  = tau - NBI;
    const int pb = tau & 1;
    float sv;
    if (t >= 0) {
      float g = biasv + appv * convT[t * NC + c] + acc[0];
      sv = 1.f / (1.f + __expf(-g));
      outS[t] = sv;
      outG[t] = g;
    } else {
      sv = ib2[tau * NC + c];
    }
    spk[pb][c] = sv;

    // rotate: acc[i] <- contributions to step (tau+1)+i
#pragma unroll
    for (int i = 0; i < NBF - 1; ++i) acc[i] = acc[i + 1];
    acc[NBF - 1] = 0.f;

    // feedback scatter (own spike, local data) — before the barrier
    {
      const u32 sp10 = pkrtz(sv, 0.f);
#pragma unroll
      for (int ib = 0; ib < 25; ++ib) {
        const uint4 w = wp[(250 + ib) * NC + c];
        acc[ib * 4 + 0] = dot2(w.x, sp10, acc[ib * 4 + 0]);
        acc[ib * 4 + 1] = dot2(w.y, sp10, acc[ib * 4 + 1]);
        acc[ib * 4 + 2] = dot2(w.z, sp10, acc[ib * 4 + 2]);
        acc[ib * 4 + 3] = dot2(w.w, sp10, acc[ib * 4 + 3]);
      }
    }

    __syncthreads();   // all 600 spikes of this batch now visible in LDS

    // coupling scatter: acc[i] += w[p][i] . sp   (1000 dot2)
    // sp gathered per-pair inside the loop: keeps peak VGPR pressure low;
    // the 25 weight loads + 100-dot2 stream per iteration hide LDS latency.
#pragma unroll 1
    for (int p = 0; p < 10; ++p) {
      const u32 s01 = selpv[p];
      const u32 sp2 = pkrtz(spk[pb][s01 & 0xffffu], spk[pb][s01 >> 16]);
#pragma unroll
      for (int ib = 0; ib < 25; ++ib) {
        const uint4 w = wp[(p * 25 + ib) * NC + c];
        acc[ib * 4 + 0] = dot2(w.x, sp2, acc[ib * 4 + 0]);
        acc[ib * 4 + 1] = dot2(w.y, sp2, acc[ib * 4 + 1]);
        acc[ib * 4 + 2] = dot2(w.z, sp2, acc[ib * 4 + 2]);
        acc[ib * 4 + 3] = dot2(w.w, sp2, acc[ib * 4 + 3]);
      }
    }
    // no second barrier needed: next write touches spk[pb^1]; the next
    // iteration's __syncthreads orders it before any reuse of spk[pb].
  }
}

extern "C" void kernel_launch(void* const* d_in, const int* in_sizes, int n_in,
                              void* d_out, int out_size, void* d_ws, size_t ws_size,
                              hipStream_t stream) {
  const float* stim = (const float*)d_in[0];   // 32x64x64
  const float* init = (const float*)d_in[1];   // 32x600x100
  const float* spat = (const float*)d_in[2];   // 600x4096
  const float* tcf  = (const float*)d_in[3];   // 600x100
  const float* ff   = (const float*)d_in[4];   // 600x100
  const float* cf   = (const float*)d_in[5];   // 600x20x100
  const float* bias = (const float*)d_in[6];   // 600x1
  const int*   sel  = (const int*)d_in[7];     // 600x20 int32
  const float* stc  = (const float*)d_in[8];   // 500
  float* out = (float*)d_out;                  // spikes 32x600x500, gensig 32x600x400

  char* ws = (char*)d_ws;
  float* applied = (float*)ws;                       //     76,800 B
  float* convT   = (float*)(ws + 76800);             //    960,000 B
  u32*   wPT     = (u32*)(ws + 1036800);             //  2,640,000 B
  u32*   selpT   = (u32*)(ws + 3676800);             //     24,000 B
  float* initT2  = (float*)(ws + 3700800);           //  7,680,000 B (end ~11.4 MB)
  (void)ws_size; (void)in_sizes; (void)n_in; (void)out_size;

  hipLaunchKernelGGL(applied_kernel, dim3(NC, NBATCH), dim3(256), 0, stream,
                     stim, spat, applied);
  hipLaunchKernelGGL(conv_kernel, dim3((NSTEP * NC + 255) / 256), dim3(256), 0,
                     stream, stc, tcf, convT);
  hipLaunchKernelGGL(pack_kernel, dim3((NC * 1100 + 255) / 256), dim3(256), 0,
                     stream, cf, ff, wPT);
  hipLaunchKernelGGL(selp_kernel, dim3((NC * 10 + 255) / 256), dim3(256), 0,
                     stream, sel, selpT);
  hipLaunchKernelGGL(initT2_kernel, dim3((NBATCH * NBI * NC + 255) / 256),
                     dim3(256), 0, stream, init, initT2);
  hipLaunchKernelGGL(copy_init_kernel,
                     dim3((NBATCH * NC * (NBI / 4) + 255) / 256), dim3(256), 0,
                     stream, (const float4*)init, (float4*)out);
  hipLaunchKernelGGL(sim_kernel, dim3(NBATCH), dim3(NC), 0, stream,
                     bias, applied, convT, (const uint4*)wPT, selpT, initT2, out);
}